// Round 9
// baseline (516.773 us; speedup 1.0000x reference)
//
#include <hip/hip_runtime.h>
#include <hip/hip_bf16.h>

// MultiAttentionHead: B=2, T=2048, E=1024, H=16, D=64
// Inputs (fp32): x[B,T,E], Wq[H,E,D], Wk[H,E,D], Wv[H,E,D], Wo[E,E]
// Output (fp32): combined @ Wo + x   [B,T,E]
//
// ws layout (ushort=fp16 elements):
//   xh/comb : 0        .. 4M    (x fp16, later overwritten by attn output)
//   wt      : 4M       .. 7.34M ([p][h][d][e] transposed QKV weights)
//   wot     : 7.34M    .. 8.39M ([j][e] transposed Wo)
//   q : 8.39M  k : 12.58M  vt : 16.78M .. 21.24M  (total ~42.5 MB)
//
// vt row stride = T + 128 = 2176 elem (4 KiB + 256 B): breaks the exact-4KiB
// stride that made all 16 fragment lanes hit the same L2/HBM channel.

#define B_ 2
#define T_ 2048
#define E_ 1024
#define H_ 16
#define D_ 64
#define VTS_ 2176   // padded vt leading dim (elements)

typedef _Float16 h8 __attribute__((ext_vector_type(8)));
typedef float f32x4 __attribute__((ext_vector_type(4)));

union U4 { uint4 u; h8 h; };

__device__ __forceinline__ float h2f(unsigned short s) {
  _Float16 h;
  __builtin_memcpy(&h, &s, 2);
  return (float)h;
}

__device__ __forceinline__ unsigned short f2h(float f) {
  _Float16 h = (_Float16)f;
  unsigned short s;
  __builtin_memcpy(&s, &h, 2);
  return s;
}

// DPP cross-lane move within a 16-lane row (full-rate VALU, no LDS pipe).
template <int CTRL>
__device__ __forceinline__ float dppmv(float x) {
  union { float f; int i; } c;
  c.f = x;
  c.i = __builtin_amdgcn_mov_dpp(c.i, CTRL, 0xF, 0xF, true);
  return c.f;
}

__device__ __forceinline__ float rowmax16(float x) {
  x = fmaxf(x, dppmv<0xB1>(x));   // lane^1
  x = fmaxf(x, dppmv<0x4E>(x));   // lane^2
  x = fmaxf(x, dppmv<0x141>(x));  // row_half_mirror
  x = fmaxf(x, dppmv<0x140>(x));  // row_mirror
  return x;
}

__device__ __forceinline__ float rowsum16(float x) {
  x += dppmv<0xB1>(x);
  x += dppmv<0x4E>(x);
  x += dppmv<0x141>(x);
  x += dppmv<0x140>(x);
  return x;
}

// ---------------------------------------------------------------------------
// Prep 0: x fp32 -> fp16.  grid = B*T*E/1024, block=256.
// ---------------------------------------------------------------------------
__global__ __launch_bounds__(256) void cvt_x(const float* __restrict__ x,
                                             unsigned short* __restrict__ xh) {
  const size_t i = ((size_t)blockIdx.x * 256 + threadIdx.x) * 4;
  const float4 f = *(const float4*)(x + i);
  ushort4 pk;
  pk.x = f2h(f.x); pk.y = f2h(f.y); pk.z = f2h(f.z); pk.w = f2h(f.w);
  *(ushort4*)(xh + i) = pk;
}

// ---------------------------------------------------------------------------
// Prep 1: Wq/Wk/Wv [h][e][d] fp32 -> wt [p][h][d][e] fp16. grid=(16,16,3).
// ---------------------------------------------------------------------------
__global__ __launch_bounds__(256) void tconv_w(
    const float* __restrict__ Wq, const float* __restrict__ Wk,
    const float* __restrict__ Wv, unsigned short* __restrict__ wt) {
  __shared__ float ts[64][65];
  const int p = blockIdx.z, h = blockIdx.y;
  const float* src = ((p == 0) ? Wq : (p == 1) ? Wk : Wv) + (size_t)h * E_ * D_;
  unsigned short* dst = wt + (size_t)(p * H_ + h) * D_ * E_;
  const int r0 = blockIdx.x * 64;  // e-tile
  const int lr = threadIdx.x >> 4, lc = (threadIdx.x & 15) * 4;
#pragma unroll
  for (int it = 0; it < 4; it++) {
    const float4 f = *(const float4*)(src + (size_t)(r0 + lr + it * 16) * D_ + lc);
    ts[lr + it * 16][lc] = f.x; ts[lr + it * 16][lc + 1] = f.y;
    ts[lr + it * 16][lc + 2] = f.z; ts[lr + it * 16][lc + 3] = f.w;
  }
  __syncthreads();
#pragma unroll
  for (int it = 0; it < 4; it++) {
    const int dr = lr + it * 16;  // d
    ushort4 pk;
    pk.x = f2h(ts[lc + 0][dr]); pk.y = f2h(ts[lc + 1][dr]);
    pk.z = f2h(ts[lc + 2][dr]); pk.w = f2h(ts[lc + 3][dr]);
    *(ushort4*)(dst + (size_t)dr * E_ + r0 + lc) = pk;
  }
}

// ---------------------------------------------------------------------------
// Prep 2: Wo [e][j] fp32 -> wot [j][e] fp16. grid=(16,16).
// ---------------------------------------------------------------------------
__global__ __launch_bounds__(256) void tconv_wo(const float* __restrict__ Wo,
                                                unsigned short* __restrict__ wot) {
  __shared__ float ts[64][65];
  const int r0 = blockIdx.x * 64;  // e-tile
  const int c0 = blockIdx.y * 64;  // j-tile
  const int lr = threadIdx.x >> 4, lc = (threadIdx.x & 15) * 4;
#pragma unroll
  for (int it = 0; it < 4; it++) {
    const float4 f = *(const float4*)(Wo + (size_t)(r0 + lr + it * 16) * E_ + c0 + lc);
    ts[lr + it * 16][lc] = f.x; ts[lr + it * 16][lc + 1] = f.y;
    ts[lr + it * 16][lc + 2] = f.z; ts[lr + it * 16][lc + 3] = f.w;
  }
  __syncthreads();
#pragma unroll
  for (int it = 0; it < 4; it++) {
    const int dr = lr + it * 16;  // j within tile
    ushort4 pk;
    pk.x = f2h(ts[lc + 0][dr]); pk.y = f2h(ts[lc + 1][dr]);
    pk.z = f2h(ts[lc + 2][dr]); pk.w = f2h(ts[lc + 3][dr]);
    *(ushort4*)(wot + (size_t)(c0 + dr) * E_ + r0 + lc) = pk;
  }
}

// ---------------------------------------------------------------------------
// Kernel 1: QKV projections via MFMA.  grid=(B*T/128, H, 3), block=256.
// v stored transposed [d][t] with padded stride VTS_.
// ---------------------------------------------------------------------------
__global__ __launch_bounds__(256) void qkv_mfma(
    const unsigned short* __restrict__ xh, const unsigned short* __restrict__ wt,
    unsigned short* __restrict__ qo, unsigned short* __restrict__ ko,
    unsigned short* __restrict__ vo)
{
  __shared__ unsigned short Cl[4][32 * 72];  // per-wave repack tile

  const int w = threadIdx.x >> 6, lane = threadIdx.x & 63;
  const int m16 = lane & 15, quad = lane >> 4;
  const int h = blockIdx.y, p = blockIdx.z;
  const int n0 = blockIdx.x * 128 + w * 32;  // wave's first token row
  const unsigned short* wb = wt + (size_t)(p * H_ + h) * D_ * E_;

  f32x4 acc[2][4];
#pragma unroll
  for (int rt = 0; rt < 2; rt++)
#pragma unroll
    for (int ct = 0; ct < 4; ct++) acc[rt][ct] = (f32x4){0.f, 0.f, 0.f, 0.f};

  for (int e0 = 0; e0 < E_; e0 += 32) {
    U4 a0, a1, bf[4];
    a0.u = *(const uint4*)(xh + (size_t)(n0 + m16) * E_ + e0 + quad * 8);
    a1.u = *(const uint4*)(xh + (size_t)(n0 + 16 + m16) * E_ + e0 + quad * 8);
#pragma unroll
    for (int ct = 0; ct < 4; ct++)
      bf[ct].u = *(const uint4*)(wb + (size_t)(ct * 16 + m16) * E_ + e0 + quad * 8);
#pragma unroll
    for (int ct = 0; ct < 4; ct++) {
      acc[0][ct] = __builtin_amdgcn_mfma_f32_16x16x32_f16(a0.h, bf[ct].h, acc[0][ct], 0, 0, 0);
      acc[1][ct] = __builtin_amdgcn_mfma_f32_16x16x32_f16(a1.h, bf[ct].h, acc[1][ct], 0, 0, 0);
    }
  }

  const int b  = (blockIdx.x * 128) >> 11;  // batch (128 | 2048, never straddles)
  const int t0 = n0 & (T_ - 1);
  const size_t bh = (size_t)(b * H_ + h);

  if (p == 2) {
#pragma unroll
    for (int rt = 0; rt < 2; rt++)
#pragma unroll
      for (int ct = 0; ct < 4; ct++) {
        const int d = ct * 16 + m16;
        const int t = t0 + rt * 16 + quad * 4;
        ushort4 pk;
        pk.x = f2h(acc[rt][ct][0]); pk.y = f2h(acc[rt][ct][1]);
        pk.z = f2h(acc[rt][ct][2]); pk.w = f2h(acc[rt][ct][3]);
        *(ushort4*)(vo + (bh * D_ + d) * (size_t)VTS_ + t) = pk;
      }
  } else {
    unsigned short* outp = (p == 0) ? qo : ko;
    unsigned short* Cw = &Cl[w][0];
#pragma unroll
    for (int rt = 0; rt < 2; rt++)
#pragma unroll
      for (int ct = 0; ct < 4; ct++)
#pragma unroll
        for (int r = 0; r < 4; r++)
          Cw[(rt * 16 + quad * 4 + r) * 72 + ct * 16 + m16] = f2h(acc[rt][ct][r]);
    const int row = lane >> 1;
    const int half = (lane & 1) * 32;
    const uint4 d0 = *(const uint4*)(Cw + row * 72 + half);
    const uint4 d1 = *(const uint4*)(Cw + row * 72 + half + 8);
    const uint4 d2 = *(const uint4*)(Cw + row * 72 + half + 16);
    const uint4 d3 = *(const uint4*)(Cw + row * 72 + half + 24);
    unsigned short* dst = outp + (bh * T_ + t0 + row) * D_ + half;
    *(uint4*)(dst)      = d0;
    *(uint4*)(dst + 8)  = d1;
    *(uint4*)(dst + 16) = d2;
    *(uint4*)(dst + 24) = d3;
  }
}

// ---------------------------------------------------------------------------
// Kernel 2: MFMA flash attention, key-parallel split, DPP softmax.
// grid=(T/32, H, B), block=256 (4 waves = 2 pairs).
// ONLY change vs round 8: vt row stride T_ -> VTS_ (channel-camping fix).
// ---------------------------------------------------------------------------
__global__ __launch_bounds__(256) void attn_kernel(
    const unsigned short* __restrict__ q, const unsigned short* __restrict__ k,
    const unsigned short* __restrict__ vt, unsigned short* __restrict__ comb)
{
  __shared__ unsigned short Pl[4][16 * 40];
  __shared__ _Float16 Om[2][2][16][66];   // [pair][kpar][row][col] (pad 66)
  __shared__ float Ml[2][2][2][16];       // [pair][kpar][{m,l}][row]

  const int w    = threadIdx.x >> 6;
  const int lane = threadIdx.x & 63;
  const int m16  = lane & 15;
  const int quad = lane >> 4;
  const int pair = w >> 1;   // which 16-row Q tile in this block
  const int kpar = w & 1;    // even/odd 32-key chunks
  const int h = blockIdx.y, b = blockIdx.z;
  const size_t bh = (size_t)(b * H_ + h);
  const int q0 = blockIdx.x * 32 + pair * 16;

  // preload Q A-frags (two K=32 halves of D=64)
  U4 aQ0, aQ1;
  {
    const unsigned short* qrow = q + (bh * T_ + q0 + m16) * (size_t)D_;
    aQ0.u = *(const uint4*)(qrow + quad * 8);
    aQ1.u = *(const uint4*)(qrow + 32 + quad * 8);
  }

  f32x4 o0 = {0.f, 0.f, 0.f, 0.f}, o1 = o0, o2 = o0, o3 = o0;
  float mrow[4] = {-1e30f, -1e30f, -1e30f, -1e30f};
  float lrow[4] = {0.f, 0.f, 0.f, 0.f};

  const unsigned short* kb  = k  + bh * (size_t)(T_ * D_);
  const unsigned short* vtb = vt + bh * (size_t)(D_ * VTS_);
  unsigned short* Pw = &Pl[w][0];

  for (int kt = kpar * 32; kt < T_; kt += 64) {
    const unsigned short* kr0 = kb + (size_t)(kt + m16) * D_ + quad * 8;
    const unsigned short* kr1 = kb + (size_t)(kt + 16 + m16) * D_ + quad * 8;
    U4 b00, b01, b10, b11;
    b00.u = *(const uint4*)(kr0);
    b01.u = *(const uint4*)(kr0 + 32);
    b10.u = *(const uint4*)(kr1);
    b11.u = *(const uint4*)(kr1 + 32);

    U4 v0, v1, v2, v3;
    v0.u = *(const uint4*)(vtb + (size_t)(m16)      * VTS_ + kt + quad * 8);
    v1.u = *(const uint4*)(vtb + (size_t)(16 + m16) * VTS_ + kt + quad * 8);
    v2.u = *(const uint4*)(vtb + (size_t)(32 + m16) * VTS_ + kt + quad * 8);
    v3.u = *(const uint4*)(vtb + (size_t)(48 + m16) * VTS_ + kt + quad * 8);

    f32x4 s0 = {0.f, 0.f, 0.f, 0.f}, s1 = s0;
    s0 = __builtin_amdgcn_mfma_f32_16x16x32_f16(aQ0.h, b00.h, s0, 0, 0, 0);
    s0 = __builtin_amdgcn_mfma_f32_16x16x32_f16(aQ1.h, b01.h, s0, 0, 0, 0);
    s1 = __builtin_amdgcn_mfma_f32_16x16x32_f16(aQ0.h, b10.h, s1, 0, 0, 0);
    s1 = __builtin_amdgcn_mfma_f32_16x16x32_f16(aQ1.h, b11.h, s1, 0, 0, 0);

    float al[4];
#pragma unroll
    for (int r = 0; r < 4; r++) {
      const float sa = s0[r] * 0.125f;   // 1/sqrt(64)
      const float sb = s1[r] * 0.125f;
      const float mt = rowmax16(fmaxf(sa, sb));
      const float mn = fmaxf(mrow[r], mt);
      const float a  = __expf(mrow[r] - mn);
      const float p0 = __expf(sa - mn);
      const float p1 = __expf(sb - mn);
      const float rs = rowsum16(p0 + p1);
      lrow[r] = lrow[r] * a + rs;
      mrow[r] = mn;
      al[r] = a;
      Pw[(quad * 4 + r) * 40 + m16]      = f2h(p0);
      Pw[(quad * 4 + r) * 40 + 16 + m16] = f2h(p1);
    }

#pragma unroll
    for (int r = 0; r < 4; r++) {
      o0[r] *= al[r]; o1[r] *= al[r]; o2[r] *= al[r]; o3[r] *= al[r];
    }

    U4 aP;
    aP.u = *(const uint4*)(Pw + m16 * 40 + quad * 8);

    o0 = __builtin_amdgcn_mfma_f32_16x16x32_f16(aP.h, v0.h, o0, 0, 0, 0);
    o1 = __builtin_amdgcn_mfma_f32_16x16x32_f16(aP.h, v1.h, o1, 0, 0, 0);
    o2 = __builtin_amdgcn_mfma_f32_16x16x32_f16(aP.h, v2.h, o2, 0, 0, 0);
    o3 = __builtin_amdgcn_mfma_f32_16x16x32_f16(aP.h, v3.h, o3, 0, 0, 0);
  }

  // ---- stage partial (m, l, O) ----
#pragma unroll
  for (int r = 0; r < 4; r++) {
    const int row = quad * 4 + r;
    Om[pair][kpar][row][m16]      = (_Float16)o0[r];
    Om[pair][kpar][row][16 + m16] = (_Float16)o1[r];
    Om[pair][kpar][row][32 + m16] = (_Float16)o2[r];
    Om[pair][kpar][row][48 + m16] = (_Float16)o3[r];
    if (m16 == 0) {   // m/l uniform across the 16-lane row group
      Ml[pair][kpar][0][row] = mrow[r];
      Ml[pair][kpar][1][row] = lrow[r];
    }
  }
  __syncthreads();

  // ---- flash merge: 128 lanes per pair, each handles 8 cols of one row ----
  const int idx = kpar * 64 + lane;  // 0..127 within the pair
  const int row = idx >> 3;          // 0..15
  const int c0  = (idx & 7) * 8;     // 0,8,...,56
  const float mA = Ml[pair][0][0][row], lA = Ml[pair][0][1][row];
  const float mB = Ml[pair][1][0][row], lB = Ml[pair][1][1][row];
  const float mS = fmaxf(mA, mB);
  const float aA = __expf(mA - mS);
  const float aB = __expf(mB - mS);
  const float inv = 1.f / (lA * aA + lB * aB);

  const int t = blockIdx.x * 32 + pair * 16 + row;
  unsigned short* dst = comb + ((size_t)b * T_ + t) * E_ + h * D_ + c0;
  union { uint4 u; unsigned short s[8]; } pk;
#pragma unroll
  for (int c = 0; c < 8; c++) {
    const float oA = (float)Om[pair][0][row][c0 + c];
    const float oB = (float)Om[pair][1][row][c0 + c];
    pk.s[c] = f2h((oA * aA + oB * aB) * inv);
  }
  *(uint4*)dst = pk.u;
}

// ---------------------------------------------------------------------------
// Kernel 3: out = comb @ Wo + x via MFMA.  grid=(B*T/128, E/64), block=256.
// ---------------------------------------------------------------------------
__global__ __launch_bounds__(256) void out_mfma(
    const unsigned short* __restrict__ comb, const unsigned short* __restrict__ wot,
    const float* __restrict__ x, float* __restrict__ out)
{
  const int w = threadIdx.x >> 6, lane = threadIdx.x & 63;
  const int m16 = lane & 15, quad = lane >> 4;
  const int n0 = blockIdx.x * 128 + w * 32;
  const int j0 = blockIdx.y * 64;

  f32x4 acc[2][4];
#pragma unroll
  for (int rt = 0; rt < 2; rt++)
#pragma unroll
    for (int ct = 0; ct < 4; ct++) acc[rt][ct] = (f32x4){0.f, 0.f, 0.f, 0.f};

  for (int e0 = 0; e0 < E_; e0 += 32) {
    U4 a0, a1, bf[4];
    a0.u = *(const uint4*)(comb + (size_t)(n0 + m16) * E_ + e0 + quad * 8);
    a1.u = *(const uint4*)(comb + (size_t)(n0 + 16 + m16) * E_ + e0 + quad * 8);
#pragma unroll
    for (int ct = 0; ct < 4; ct++)
      bf[ct].u = *(const uint4*)(wot + (size_t)(j0 + ct * 16 + m16) * E_ + e0 + quad * 8);
#pragma unroll
    for (int ct = 0; ct < 4; ct++) {
      acc[0][ct] = __builtin_amdgcn_mfma_f32_16x16x32_f16(a0.h, bf[ct].h, acc[0][ct], 0, 0, 0);
      acc[1][ct] = __builtin_amdgcn_mfma_f32_16x16x32_f16(a1.h, bf[ct].h, acc[1][ct], 0, 0, 0);
    }
  }

#pragma unroll
  for (int rt = 0; rt < 2; rt++)
#pragma unroll
    for (int r = 0; r < 4; r++) {
      const int n = n0 + rt * 16 + quad * 4 + r;
      const float* xr = x + (size_t)n * E_ + j0;
      float* orow = out + (size_t)n * E_ + j0;
#pragma unroll
      for (int ct = 0; ct < 4; ct++) {
        const int j = ct * 16 + m16;
        orow[j] = acc[rt][ct][r] + xr[j];
      }
    }
}

// ---------------------------------------------------------------------------
extern "C" void kernel_launch(void* const* d_in, const int* in_sizes, int n_in,
                              void* d_out, int out_size, void* d_ws, size_t ws_size,
                              hipStream_t stream) {
  (void)in_sizes; (void)n_in; (void)out_size; (void)ws_size;

  const float* x  = (const float*)d_in[0];
  const float* Wq = (const float*)d_in[1];
  const float* Wk = (const float*)d_in[2];
  const float* Wv = (const float*)d_in[3];
  const float* Wo = (const float*)d_in[4];
  float* out = (float*)d_out;

  unsigned short* ws0  = (unsigned short*)d_ws;
  unsigned short* xh   = ws0;                    // 4M elems (aliases comb)
  unsigned short* wt   = ws0 + 4194304;          // 3M
  unsigned short* wot  = ws0 + 7340032;          // 1M
  unsigned short* qh   = ws0 + 8388608;          // 4M
  unsigned short* kh   = ws0 + 12582912;         // 4M
  unsigned short* vth  = ws0 + 16777216;         // 32*64*2176 = 4.46M (padded)
  unsigned short* comb = xh;                     // alias: xh dead after qkv

  cvt_x<<<dim3(B_ * T_ * E_ / 1024), dim3(256), 0, stream>>>(x, xh);
  tconv_w<<<dim3(E_ / 64, H_, 3), dim3(256), 0, stream>>>(Wq, Wk, Wv, wt);
  tconv_wo<<<dim3(E_ / 64, E_ / 64), dim3(256), 0, stream>>>(Wo, wot);

  qkv_mfma<<<dim3(B_ * T_ / 128, H_, 3), dim3(256), 0, stream>>>(xh, wt, qh, kh, vth);

  attn_kernel<<<dim3(T_ / 32, H_, B_), dim3(256), 0, stream>>>(qh, kh, vth, comb);

  out_mfma<<<dim3(B_ * T_ / 128, E_ / 64), dim3(256), 0, stream>>>(comb, wot, x, out);
}

// Round 10
// 372.128 us; speedup vs baseline: 1.3887x; 1.3887x over previous
//
#include <hip/hip_runtime.h>
#include <hip/hip_bf16.h>

// MultiAttentionHead: B=2, T=2048, E=1024, H=16, D=64
// Inputs (fp32): x[B,T,E], Wq[H,E,D], Wk[H,E,D], Wv[H,E,D], Wo[E,E]
// Output (fp32): combined @ Wo + x   [B,T,E]
//
// ws layout (ushort=fp16 elements):
//   xh/comb : 0        .. 4M    (x fp16, later overwritten by attn output)
//   wt      : 4M       .. 7.34M ([p][h][d][e] transposed QKV weights)
//   wot     : 7.34M    .. 8.39M ([j][e] transposed Wo)
//   q : 8.39M  k : 12.58M  vt : 16.78M .. 21.24M  (total ~42.5 MB)

#define B_ 2
#define T_ 2048
#define E_ 1024
#define H_ 16
#define D_ 64
#define VTS_ 2176   // padded vt leading dim (elements)
#define LD_ 72      // LDS tile row stride (elements; 64 + 8, keeps 16B align)

typedef _Float16 h8 __attribute__((ext_vector_type(8)));
typedef float f32x4 __attribute__((ext_vector_type(4)));

union U4 { uint4 u; h8 h; };

__device__ __forceinline__ float h2f(unsigned short s) {
  _Float16 h;
  __builtin_memcpy(&h, &s, 2);
  return (float)h;
}

__device__ __forceinline__ unsigned short f2h(float f) {
  _Float16 h = (_Float16)f;
  unsigned short s;
  __builtin_memcpy(&s, &h, 2);
  return s;
}

// DPP cross-lane move within a 16-lane row (full-rate VALU, no LDS pipe).
template <int CTRL>
__device__ __forceinline__ float dppmv(float x) {
  union { float f; int i; } c;
  c.f = x;
  c.i = __builtin_amdgcn_mov_dpp(c.i, CTRL, 0xF, 0xF, true);
  return c.f;
}

__device__ __forceinline__ float rowmax16(float x) {
  x = fmaxf(x, dppmv<0xB1>(x));   // lane^1
  x = fmaxf(x, dppmv<0x4E>(x));   // lane^2
  x = fmaxf(x, dppmv<0x141>(x));  // row_half_mirror
  x = fmaxf(x, dppmv<0x140>(x));  // row_mirror
  return x;
}

__device__ __forceinline__ float rowsum16(float x) {
  x += dppmv<0xB1>(x);
  x += dppmv<0x4E>(x);
  x += dppmv<0x141>(x);
  x += dppmv<0x140>(x);
  return x;
}

// ---------------------------------------------------------------------------
// Prep 0: x fp32 -> fp16.  grid = B*T*E/1024, block=256.
// ---------------------------------------------------------------------------
__global__ __launch_bounds__(256) void cvt_x(const float* __restrict__ x,
                                             unsigned short* __restrict__ xh) {
  const size_t i = ((size_t)blockIdx.x * 256 + threadIdx.x) * 4;
  const float4 f = *(const float4*)(x + i);
  ushort4 pk;
  pk.x = f2h(f.x); pk.y = f2h(f.y); pk.z = f2h(f.z); pk.w = f2h(f.w);
  *(ushort4*)(xh + i) = pk;
}

// ---------------------------------------------------------------------------
// Prep 1: Wq/Wk/Wv [h][e][d] fp32 -> wt [p][h][d][e] fp16. grid=(16,16,3).
// ---------------------------------------------------------------------------
__global__ __launch_bounds__(256) void tconv_w(
    const float* __restrict__ Wq, const float* __restrict__ Wk,
    const float* __restrict__ Wv, unsigned short* __restrict__ wt) {
  __shared__ float ts[64][65];
  const int p = blockIdx.z, h = blockIdx.y;
  const float* src = ((p == 0) ? Wq : (p == 1) ? Wk : Wv) + (size_t)h * E_ * D_;
  unsigned short* dst = wt + (size_t)(p * H_ + h) * D_ * E_;
  const int r0 = blockIdx.x * 64;  // e-tile
  const int lr = threadIdx.x >> 4, lc = (threadIdx.x & 15) * 4;
#pragma unroll
  for (int it = 0; it < 4; it++) {
    const float4 f = *(const float4*)(src + (size_t)(r0 + lr + it * 16) * D_ + lc);
    ts[lr + it * 16][lc] = f.x; ts[lr + it * 16][lc + 1] = f.y;
    ts[lr + it * 16][lc + 2] = f.z; ts[lr + it * 16][lc + 3] = f.w;
  }
  __syncthreads();
#pragma unroll
  for (int it = 0; it < 4; it++) {
    const int dr = lr + it * 16;  // d
    ushort4 pk;
    pk.x = f2h(ts[lc + 0][dr]); pk.y = f2h(ts[lc + 1][dr]);
    pk.z = f2h(ts[lc + 2][dr]); pk.w = f2h(ts[lc + 3][dr]);
    *(ushort4*)(dst + (size_t)dr * E_ + r0 + lc) = pk;
  }
}

// ---------------------------------------------------------------------------
// Prep 2: Wo [e][j] fp32 -> wot [j][e] fp16. grid=(16,16).
// ---------------------------------------------------------------------------
__global__ __launch_bounds__(256) void tconv_wo(const float* __restrict__ Wo,
                                                unsigned short* __restrict__ wot) {
  __shared__ float ts[64][65];
  const int r0 = blockIdx.x * 64;  // e-tile
  const int c0 = blockIdx.y * 64;  // j-tile
  const int lr = threadIdx.x >> 4, lc = (threadIdx.x & 15) * 4;
#pragma unroll
  for (int it = 0; it < 4; it++) {
    const float4 f = *(const float4*)(Wo + (size_t)(r0 + lr + it * 16) * E_ + c0 + lc);
    ts[lr + it * 16][lc] = f.x; ts[lr + it * 16][lc + 1] = f.y;
    ts[lr + it * 16][lc + 2] = f.z; ts[lr + it * 16][lc + 3] = f.w;
  }
  __syncthreads();
#pragma unroll
  for (int it = 0; it < 4; it++) {
    const int dr = lr + it * 16;  // j within tile
    ushort4 pk;
    pk.x = f2h(ts[lc + 0][dr]); pk.y = f2h(ts[lc + 1][dr]);
    pk.z = f2h(ts[lc + 2][dr]); pk.w = f2h(ts[lc + 3][dr]);
    *(ushort4*)(wot + (size_t)(c0 + dr) * E_ + r0 + lc) = pk;
  }
}

// ---------------------------------------------------------------------------
// Kernel 1: QKV projections via MFMA.  grid=(B*T/128, H, 3), block=256.
// (unchanged from round 9 — validated)
// ---------------------------------------------------------------------------
__global__ __launch_bounds__(256) void qkv_mfma(
    const unsigned short* __restrict__ xh, const unsigned short* __restrict__ wt,
    unsigned short* __restrict__ qo, unsigned short* __restrict__ ko,
    unsigned short* __restrict__ vo)
{
  __shared__ unsigned short Cl[4][32 * 72];  // per-wave repack tile

  const int w = threadIdx.x >> 6, lane = threadIdx.x & 63;
  const int m16 = lane & 15, quad = lane >> 4;
  const int h = blockIdx.y, p = blockIdx.z;
  const int n0 = blockIdx.x * 128 + w * 32;  // wave's first token row
  const unsigned short* wb = wt + (size_t)(p * H_ + h) * D_ * E_;

  f32x4 acc[2][4];
#pragma unroll
  for (int rt = 0; rt < 2; rt++)
#pragma unroll
    for (int ct = 0; ct < 4; ct++) acc[rt][ct] = (f32x4){0.f, 0.f, 0.f, 0.f};

  for (int e0 = 0; e0 < E_; e0 += 32) {
    U4 a0, a1, bf[4];
    a0.u = *(const uint4*)(xh + (size_t)(n0 + m16) * E_ + e0 + quad * 8);
    a1.u = *(const uint4*)(xh + (size_t)(n0 + 16 + m16) * E_ + e0 + quad * 8);
#pragma unroll
    for (int ct = 0; ct < 4; ct++)
      bf[ct].u = *(const uint4*)(wb + (size_t)(ct * 16 + m16) * E_ + e0 + quad * 8);
#pragma unroll
    for (int ct = 0; ct < 4; ct++) {
      acc[0][ct] = __builtin_amdgcn_mfma_f32_16x16x32_f16(a0.h, bf[ct].h, acc[0][ct], 0, 0, 0);
      acc[1][ct] = __builtin_amdgcn_mfma_f32_16x16x32_f16(a1.h, bf[ct].h, acc[1][ct], 0, 0, 0);
    }
  }

  const int b  = (blockIdx.x * 128) >> 11;  // batch (128 | 2048, never straddles)
  const int t0 = n0 & (T_ - 1);
  const size_t bh = (size_t)(b * H_ + h);

  if (p == 2) {
#pragma unroll
    for (int rt = 0; rt < 2; rt++)
#pragma unroll
      for (int ct = 0; ct < 4; ct++) {
        const int d = ct * 16 + m16;
        const int t = t0 + rt * 16 + quad * 4;
        ushort4 pk;
        pk.x = f2h(acc[rt][ct][0]); pk.y = f2h(acc[rt][ct][1]);
        pk.z = f2h(acc[rt][ct][2]); pk.w = f2h(acc[rt][ct][3]);
        *(ushort4*)(vo + (bh * D_ + d) * (size_t)VTS_ + t) = pk;
      }
  } else {
    unsigned short* outp = (p == 0) ? qo : ko;
    unsigned short* Cw = &Cl[w][0];
#pragma unroll
    for (int rt = 0; rt < 2; rt++)
#pragma unroll
      for (int ct = 0; ct < 4; ct++)
#pragma unroll
        for (int r = 0; r < 4; r++)
          Cw[(rt * 16 + quad * 4 + r) * 72 + ct * 16 + m16] = f2h(acc[rt][ct][r]);
    const int row = lane >> 1;
    const int half = (lane & 1) * 32;
    const uint4 d0 = *(const uint4*)(Cw + row * 72 + half);
    const uint4 d1 = *(const uint4*)(Cw + row * 72 + half + 8);
    const uint4 d2 = *(const uint4*)(Cw + row * 72 + half + 16);
    const uint4 d3 = *(const uint4*)(Cw + row * 72 + half + 24);
    unsigned short* dst = outp + (bh * T_ + t0 + row) * D_ + half;
    *(uint4*)(dst)      = d0;
    *(uint4*)(dst + 8)  = d1;
    *(uint4*)(dst + 16) = d2;
    *(uint4*)(dst + 24) = d3;
  }
}

// ---------------------------------------------------------------------------
// Kernel 2: MFMA flash attention v4 — block-cooperative COALESCED staging.
// grid=(T/64, H, B), block=256 (4 waves = 4 Q-tiles of 16 rows).
// Per 64-key step: stage K[64 keys][64 d] and V[d][key] tiles into LDS with
// lane-contiguous uint4 loads, then fragments via ds_read_b128.
// Softmax/P-roundtrip/epilogue = round-9-validated code.
// ---------------------------------------------------------------------------
__global__ __launch_bounds__(256) void attn_kernel(
    const unsigned short* __restrict__ q, const unsigned short* __restrict__ k,
    const unsigned short* __restrict__ vt, unsigned short* __restrict__ comb)
{
  __shared__ unsigned short Kt[64 * LD_];   // [key][d]
  __shared__ unsigned short Vt[64 * LD_];   // [d][key]
  __shared__ unsigned short Pl[4][16 * LD_];

  const int tid  = threadIdx.x;
  const int w    = tid >> 6;
  const int lane = tid & 63;
  const int m16  = lane & 15;
  const int quad = lane >> 4;
  const int h = blockIdx.y, b = blockIdx.z;
  const size_t bh = (size_t)(b * H_ + h);
  const int q0 = blockIdx.x * 64 + w * 16;

  // preload Q A-frags (two K=32 halves of D=64); once per wave, gather ok
  U4 aQ0, aQ1;
  {
    const unsigned short* qrow = q + (bh * T_ + q0 + m16) * (size_t)D_;
    aQ0.u = *(const uint4*)(qrow + quad * 8);
    aQ1.u = *(const uint4*)(qrow + 32 + quad * 8);
  }

  f32x4 o0 = {0.f, 0.f, 0.f, 0.f}, o1 = o0, o2 = o0, o3 = o0;
  float mrow[4] = {-1e30f, -1e30f, -1e30f, -1e30f};
  float lrow[4] = {0.f, 0.f, 0.f, 0.f};

  const unsigned short* kb  = k  + bh * (size_t)(T_ * D_);
  const unsigned short* vtb = vt + bh * (size_t)(D_ * VTS_);
  unsigned short* Pw = &Pl[w][0];

  // staging indices: thread -> (row sr, col sc), lane-contiguous within rows
  const int sr = tid >> 3;          // 0..31
  const int sc = (tid & 7) * 8;     // 0,8,...,56

  for (int kt = 0; kt < T_; kt += 64) {
    __syncthreads();  // all waves done reading previous tiles
    {
      const uint4 ka = *(const uint4*)(kb + (size_t)(kt + sr) * D_ + sc);
      const uint4 kc = *(const uint4*)(kb + (size_t)(kt + 32 + sr) * D_ + sc);
      *(uint4*)(Kt + sr * LD_ + sc)        = ka;
      *(uint4*)(Kt + (32 + sr) * LD_ + sc) = kc;
      const uint4 va = *(const uint4*)(vtb + (size_t)sr * VTS_ + kt + sc);
      const uint4 vc = *(const uint4*)(vtb + (size_t)(32 + sr) * VTS_ + kt + sc);
      *(uint4*)(Vt + sr * LD_ + sc)        = va;
      *(uint4*)(Vt + (32 + sr) * LD_ + sc) = vc;
    }
    __syncthreads();

    // ---- S = Q K^T over 4 key sub-tiles of 16 ----
    f32x4 s[4];
#pragma unroll
    for (int ct = 0; ct < 4; ct++) {
      U4 kf0, kf1;
      kf0.u = *(const uint4*)(Kt + (ct * 16 + m16) * LD_ + quad * 8);
      kf1.u = *(const uint4*)(Kt + (ct * 16 + m16) * LD_ + 32 + quad * 8);
      f32x4 z = {0.f, 0.f, 0.f, 0.f};
      z = __builtin_amdgcn_mfma_f32_16x16x32_f16(aQ0.h, kf0.h, z, 0, 0, 0);
      z = __builtin_amdgcn_mfma_f32_16x16x32_f16(aQ1.h, kf1.h, z, 0, 0, 0);
      s[ct] = z;
    }

    // ---- online softmax over 64 keys (DPP row reductions; validated) ----
    float al[4];
#pragma unroll
    for (int r = 0; r < 4; r++) {
      const float s0 = s[0][r] * 0.125f;
      const float s1 = s[1][r] * 0.125f;
      const float s2 = s[2][r] * 0.125f;
      const float s3 = s[3][r] * 0.125f;
      const float mt = rowmax16(fmaxf(fmaxf(s0, s1), fmaxf(s2, s3)));
      const float mn = fmaxf(mrow[r], mt);
      const float a  = __expf(mrow[r] - mn);
      const float p0 = __expf(s0 - mn);
      const float p1 = __expf(s1 - mn);
      const float p2 = __expf(s2 - mn);
      const float p3 = __expf(s3 - mn);
      const float rs = rowsum16(p0 + p1 + p2 + p3);
      lrow[r] = lrow[r] * a + rs;
      mrow[r] = mn;
      al[r] = a;
      unsigned short* Pr = Pw + (quad * 4 + r) * LD_ + m16;
      Pr[0]  = f2h(p0);
      Pr[16] = f2h(p1);
      Pr[32] = f2h(p2);
      Pr[48] = f2h(p3);
    }

#pragma unroll
    for (int r = 0; r < 4; r++) {
      o0[r] *= al[r]; o1[r] *= al[r]; o2[r] *= al[r]; o3[r] *= al[r];
    }

    // ---- P: C-layout -> A-layout via per-wave LDS (same-wave, in-order) ----
    U4 aP0, aP1;
    aP0.u = *(const uint4*)(Pw + m16 * LD_ + quad * 8);
    aP1.u = *(const uint4*)(Pw + m16 * LD_ + 32 + quad * 8);

    // ---- PV: 2 key-chunks x 4 d-tiles ----
#pragma unroll
    for (int ct = 0; ct < 4; ct++) {
      U4 vf0, vf1;
      vf0.u = *(const uint4*)(Vt + (ct * 16 + m16) * LD_ + quad * 8);
      vf1.u = *(const uint4*)(Vt + (ct * 16 + m16) * LD_ + 32 + quad * 8);
      f32x4* op = (ct == 0) ? &o0 : (ct == 1) ? &o1 : (ct == 2) ? &o2 : &o3;
      *op = __builtin_amdgcn_mfma_f32_16x16x32_f16(aP0.h, vf0.h, *op, 0, 0, 0);
      *op = __builtin_amdgcn_mfma_f32_16x16x32_f16(aP1.h, vf1.h, *op, 0, 0, 0);
    }
  }

  // ---- epilogue: O /= l, store fp16 to comb[b][t][h*64 + d] ----
#pragma unroll
  for (int r = 0; r < 4; r++) {
    const float inv = 1.f / lrow[r];
    const int t = q0 + quad * 4 + r;
    unsigned short* dst = comb + ((size_t)b * T_ + t) * E_ + h * D_;
    dst[m16]      = f2h(o0[r] * inv);
    dst[16 + m16] = f2h(o1[r] * inv);
    dst[32 + m16] = f2h(o2[r] * inv);
    dst[48 + m16] = f2h(o3[r] * inv);
  }
}

// ---------------------------------------------------------------------------
// Kernel 3: out = comb @ Wo + x via MFMA.  grid=(B*T/128, E/64), block=256.
// (unchanged from round 9 — validated)
// ---------------------------------------------------------------------------
__global__ __launch_bounds__(256) void out_mfma(
    const unsigned short* __restrict__ comb, const unsigned short* __restrict__ wot,
    const float* __restrict__ x, float* __restrict__ out)
{
  const int w = threadIdx.x >> 6, lane = threadIdx.x & 63;
  const int m16 = lane & 15, quad = lane >> 4;
  const int n0 = blockIdx.x * 128 + w * 32;
  const int j0 = blockIdx.y * 64;

  f32x4 acc[2][4];
#pragma unroll
  for (int rt = 0; rt < 2; rt++)
#pragma unroll
    for (int ct = 0; ct < 4; ct++) acc[rt][ct] = (f32x4){0.f, 0.f, 0.f, 0.f};

  for (int e0 = 0; e0 < E_; e0 += 32) {
    U4 a0, a1, bf[4];
    a0.u = *(const uint4*)(comb + (size_t)(n0 + m16) * E_ + e0 + quad * 8);
    a1.u = *(const uint4*)(comb + (size_t)(n0 + 16 + m16) * E_ + e0 + quad * 8);
#pragma unroll
    for (int ct = 0; ct < 4; ct++)
      bf[ct].u = *(const uint4*)(wot + (size_t)(j0 + ct * 16 + m16) * E_ + e0 + quad * 8);
#pragma unroll
    for (int ct = 0; ct < 4; ct++) {
      acc[0][ct] = __builtin_amdgcn_mfma_f32_16x16x32_f16(a0.h, bf[ct].h, acc[0][ct], 0, 0, 0);
      acc[1][ct] = __builtin_amdgcn_mfma_f32_16x16x32_f16(a1.h, bf[ct].h, acc[1][ct], 0, 0, 0);
    }
  }

#pragma unroll
  for (int rt = 0; rt < 2; rt++)
#pragma unroll
    for (int r = 0; r < 4; r++) {
      const int n = n0 + rt * 16 + quad * 4 + r;
      const float* xr = x + (size_t)n * E_ + j0;
      float* orow = out + (size_t)n * E_ + j0;
#pragma unroll
      for (int ct = 0; ct < 4; ct++) {
        const int j = ct * 16 + m16;
        orow[j] = acc[rt][ct][r] + xr[j];
      }
    }
}

// ---------------------------------------------------------------------------
extern "C" void kernel_launch(void* const* d_in, const int* in_sizes, int n_in,
                              void* d_out, int out_size, void* d_ws, size_t ws_size,
                              hipStream_t stream) {
  (void)in_sizes; (void)n_in; (void)out_size; (void)ws_size;

  const float* x  = (const float*)d_in[0];
  const float* Wq = (const float*)d_in[1];
  const float* Wk = (const float*)d_in[2];
  const float* Wv = (const float*)d_in[3];
  const float* Wo = (const float*)d_in[4];
  float* out = (float*)d_out;

  unsigned short* ws0  = (unsigned short*)d_ws;
  unsigned short* xh   = ws0;                    // 4M elems (aliases comb)
  unsigned short* wt   = ws0 + 4194304;          // 3M
  unsigned short* wot  = ws0 + 7340032;          // 1M
  unsigned short* qh   = ws0 + 8388608;          // 4M
  unsigned short* kh   = ws0 + 12582912;         // 4M
  unsigned short* vth  = ws0 + 16777216;         // 32*64*2176 = 4.46M (padded)
  unsigned short* comb = xh;                     // alias: xh dead after qkv

  cvt_x<<<dim3(B_ * T_ * E_ / 1024), dim3(256), 0, stream>>>(x, xh);
  tconv_w<<<dim3(E_ / 64, H_, 3), dim3(256), 0, stream>>>(Wq, Wk, Wv, wt);
  tconv_wo<<<dim3(E_ / 64, E_ / 64), dim3(256), 0, stream>>>(Wo, wot);

  qkv_mfma<<<dim3(B_ * T_ / 128, H_, 3), dim3(256), 0, stream>>>(xh, wt, qh, kh, vth);

  attn_kernel<<<dim3(T_ / 64, H_, B_), dim3(256), 0, stream>>>(qh, kh, vth, comb);

  out_mfma<<<dim3(B_ * T_ / 128, E_ / 64), dim3(256), 0, stream>>>(comb, wot, x, out);
}

// Round 11
// 240.339 us; speedup vs baseline: 2.1502x; 1.5483x over previous
//
#include <hip/hip_runtime.h>
#include <hip/hip_bf16.h>

// MultiAttentionHead: B=2, T=2048, E=1024, H=16, D=64
// Inputs (fp32): x[B,T,E], Wq[H,E,D], Wk[H,E,D], Wv[H,E,D], Wo[E,E]
// Output (fp32): combined @ Wo + x   [B,T,E]
//
// ws layout (ushort=fp16 elements):
//   xh/comb : 0        .. 4M    (x fp16, later overwritten by attn output)
//   wt      : 4M       .. 7.34M ([p][h][d][e] transposed QKV weights)
//   wot     : 7.34M    .. 8.39M ([j][e] transposed Wo)
//   q : 8.39M  k : 12.58M  vt : 16.78M .. 21.24M  (total ~42.5 MB)
//
// Key lesson (r10): direct MFMA fragment gathers (adjacent lanes striding by
// the row pitch) saturate the per-CU address pipeline. ALL GEMM kernels now
// stage tiles into LDS with lane-contiguous loads, fragments via ds_read_b128.

#define B_ 2
#define T_ 2048
#define E_ 1024
#define H_ 16
#define D_ 64
#define VTS_ 2176   // padded vt leading dim (elements)
#define LD_ 72      // LDS tile row stride (elements; 64 + 8, keeps 16B align)

typedef _Float16 h8 __attribute__((ext_vector_type(8)));
typedef float f32x4 __attribute__((ext_vector_type(4)));

union U4 { uint4 u; h8 h; };

__device__ __forceinline__ float h2f(unsigned short s) {
  _Float16 h;
  __builtin_memcpy(&h, &s, 2);
  return (float)h;
}

__device__ __forceinline__ unsigned short f2h(float f) {
  _Float16 h = (_Float16)f;
  unsigned short s;
  __builtin_memcpy(&s, &h, 2);
  return s;
}

// DPP cross-lane move within a 16-lane row (full-rate VALU, no LDS pipe).
template <int CTRL>
__device__ __forceinline__ float dppmv(float x) {
  union { float f; int i; } c;
  c.f = x;
  c.i = __builtin_amdgcn_mov_dpp(c.i, CTRL, 0xF, 0xF, true);
  return c.f;
}

__device__ __forceinline__ float rowmax16(float x) {
  x = fmaxf(x, dppmv<0xB1>(x));   // lane^1
  x = fmaxf(x, dppmv<0x4E>(x));   // lane^2
  x = fmaxf(x, dppmv<0x141>(x));  // row_half_mirror
  x = fmaxf(x, dppmv<0x140>(x));  // row_mirror
  return x;
}

__device__ __forceinline__ float rowsum16(float x) {
  x += dppmv<0xB1>(x);
  x += dppmv<0x4E>(x);
  x += dppmv<0x141>(x);
  x += dppmv<0x140>(x);
  return x;
}

// ---------------------------------------------------------------------------
// Prep 0: x fp32 -> fp16.  grid = B*T*E/1024, block=256.
// ---------------------------------------------------------------------------
__global__ __launch_bounds__(256) void cvt_x(const float* __restrict__ x,
                                             unsigned short* __restrict__ xh) {
  const size_t i = ((size_t)blockIdx.x * 256 + threadIdx.x) * 4;
  const float4 f = *(const float4*)(x + i);
  ushort4 pk;
  pk.x = f2h(f.x); pk.y = f2h(f.y); pk.z = f2h(f.z); pk.w = f2h(f.w);
  *(ushort4*)(xh + i) = pk;
}

// ---------------------------------------------------------------------------
// Prep 1: Wq/Wk/Wv [h][e][d] fp32 -> wt [p][h][d][e] fp16. grid=(16,16,3).
// ---------------------------------------------------------------------------
__global__ __launch_bounds__(256) void tconv_w(
    const float* __restrict__ Wq, const float* __restrict__ Wk,
    const float* __restrict__ Wv, unsigned short* __restrict__ wt) {
  __shared__ float ts[64][65];
  const int p = blockIdx.z, h = blockIdx.y;
  const float* src = ((p == 0) ? Wq : (p == 1) ? Wk : Wv) + (size_t)h * E_ * D_;
  unsigned short* dst = wt + (size_t)(p * H_ + h) * D_ * E_;
  const int r0 = blockIdx.x * 64;  // e-tile
  const int lr = threadIdx.x >> 4, lc = (threadIdx.x & 15) * 4;
#pragma unroll
  for (int it = 0; it < 4; it++) {
    const float4 f = *(const float4*)(src + (size_t)(r0 + lr + it * 16) * D_ + lc);
    ts[lr + it * 16][lc] = f.x; ts[lr + it * 16][lc + 1] = f.y;
    ts[lr + it * 16][lc + 2] = f.z; ts[lr + it * 16][lc + 3] = f.w;
  }
  __syncthreads();
#pragma unroll
  for (int it = 0; it < 4; it++) {
    const int dr = lr + it * 16;  // d
    ushort4 pk;
    pk.x = f2h(ts[lc + 0][dr]); pk.y = f2h(ts[lc + 1][dr]);
    pk.z = f2h(ts[lc + 2][dr]); pk.w = f2h(ts[lc + 3][dr]);
    *(ushort4*)(dst + (size_t)dr * E_ + r0 + lc) = pk;
  }
}

// ---------------------------------------------------------------------------
// Prep 2: Wo [e][j] fp32 -> wot [j][e] fp16. grid=(16,16).
// ---------------------------------------------------------------------------
__global__ __launch_bounds__(256) void tconv_wo(const float* __restrict__ Wo,
                                                unsigned short* __restrict__ wot) {
  __shared__ float ts[64][65];
  const int r0 = blockIdx.x * 64;  // e-tile
  const int c0 = blockIdx.y * 64;  // j-tile
  const int lr = threadIdx.x >> 4, lc = (threadIdx.x & 15) * 4;
#pragma unroll
  for (int it = 0; it < 4; it++) {
    const float4 f = *(const float4*)(Wo + (size_t)(r0 + lr + it * 16) * E_ + c0 + lc);
    ts[lr + it * 16][lc] = f.x; ts[lr + it * 16][lc + 1] = f.y;
    ts[lr + it * 16][lc + 2] = f.z; ts[lr + it * 16][lc + 3] = f.w;
  }
  __syncthreads();
#pragma unroll
  for (int it = 0; it < 4; it++) {
    const int dr = lr + it * 16;  // j within tile
    ushort4 pk;
    pk.x = f2h(ts[lc + 0][dr]); pk.y = f2h(ts[lc + 1][dr]);
    pk.z = f2h(ts[lc + 2][dr]); pk.w = f2h(ts[lc + 3][dr]);
    *(ushort4*)(wot + (size_t)(c0 + dr) * E_ + r0 + lc) = pk;
  }
}

// ---------------------------------------------------------------------------
// Kernel 1: QKV projections via MFMA, coalesced LDS staging.
// grid=(B*T/128, H, 3), block=256 (4 waves).
// Block: 128 tokens x 64 outs. Per 64-wide e-step: stage x(128x64) and
// W(64x64) tiles coalesced, fragments via ds_read_b128.
// ---------------------------------------------------------------------------
__global__ __launch_bounds__(256) void qkv_mfma(
    const unsigned short* __restrict__ xh, const unsigned short* __restrict__ wt,
    unsigned short* __restrict__ qo, unsigned short* __restrict__ ko,
    unsigned short* __restrict__ vo)
{
  __shared__ unsigned short xs[128 * LD_];   // [token][e]
  __shared__ unsigned short wsb[64 * LD_];   // [d][e]
  __shared__ unsigned short Cl[4][32 * 72];  // per-wave repack tile

  const int tid = threadIdx.x;
  const int w = tid >> 6, lane = tid & 63;
  const int m16 = lane & 15, quad = lane >> 4;
  const int h = blockIdx.y, p = blockIdx.z;
  const int n0 = blockIdx.x * 128;           // block token base
  const unsigned short* wb = wt + (size_t)(p * H_ + h) * D_ * E_;

  const int sr = tid >> 3;          // 0..31
  const int sc = (tid & 7) * 8;     // 0,8,...,56

  f32x4 acc[2][4];
#pragma unroll
  for (int rt = 0; rt < 2; rt++)
#pragma unroll
    for (int ct = 0; ct < 4; ct++) acc[rt][ct] = (f32x4){0.f, 0.f, 0.f, 0.f};

  for (int e0 = 0; e0 < E_; e0 += 64) {
    __syncthreads();
#pragma unroll
    for (int it = 0; it < 4; it++) {
      const int row = it * 32 + sr;
      *(uint4*)(xs + row * LD_ + sc) =
          *(const uint4*)(xh + (size_t)(n0 + row) * E_ + e0 + sc);
    }
#pragma unroll
    for (int it = 0; it < 2; it++) {
      const int row = it * 32 + sr;
      *(uint4*)(wsb + row * LD_ + sc) =
          *(const uint4*)(wb + (size_t)row * E_ + e0 + sc);
    }
    __syncthreads();

#pragma unroll
    for (int kk = 0; kk < 64; kk += 32) {
      U4 a0, a1, bf[4];
      a0.u = *(const uint4*)(xs + (w * 32 + m16) * LD_ + kk + quad * 8);
      a1.u = *(const uint4*)(xs + (w * 32 + 16 + m16) * LD_ + kk + quad * 8);
#pragma unroll
      for (int ct = 0; ct < 4; ct++)
        bf[ct].u = *(const uint4*)(wsb + (ct * 16 + m16) * LD_ + kk + quad * 8);
#pragma unroll
      for (int ct = 0; ct < 4; ct++) {
        acc[0][ct] = __builtin_amdgcn_mfma_f32_16x16x32_f16(a0.h, bf[ct].h, acc[0][ct], 0, 0, 0);
        acc[1][ct] = __builtin_amdgcn_mfma_f32_16x16x32_f16(a1.h, bf[ct].h, acc[1][ct], 0, 0, 0);
      }
    }
  }

  const int nw = n0 + w * 32;               // wave token base
  const int b  = n0 >> 11;                  // batch (128 | 2048, never straddles)
  const int t0 = nw & (T_ - 1);
  const size_t bh = (size_t)(b * H_ + h);

  if (p == 2) {
#pragma unroll
    for (int rt = 0; rt < 2; rt++)
#pragma unroll
      for (int ct = 0; ct < 4; ct++) {
        const int d = ct * 16 + m16;
        const int t = t0 + rt * 16 + quad * 4;
        ushort4 pk;
        pk.x = f2h(acc[rt][ct][0]); pk.y = f2h(acc[rt][ct][1]);
        pk.z = f2h(acc[rt][ct][2]); pk.w = f2h(acc[rt][ct][3]);
        *(ushort4*)(vo + (bh * D_ + d) * (size_t)VTS_ + t) = pk;
      }
  } else {
    unsigned short* outp = (p == 0) ? qo : ko;
    unsigned short* Cw = &Cl[w][0];
#pragma unroll
    for (int rt = 0; rt < 2; rt++)
#pragma unroll
      for (int ct = 0; ct < 4; ct++)
#pragma unroll
        for (int r = 0; r < 4; r++)
          Cw[(rt * 16 + quad * 4 + r) * 72 + ct * 16 + m16] = f2h(acc[rt][ct][r]);
    const int row = lane >> 1;
    const int half = (lane & 1) * 32;
    const uint4 d0 = *(const uint4*)(Cw + row * 72 + half);
    const uint4 d1 = *(const uint4*)(Cw + row * 72 + half + 8);
    const uint4 d2 = *(const uint4*)(Cw + row * 72 + half + 16);
    const uint4 d3 = *(const uint4*)(Cw + row * 72 + half + 24);
    unsigned short* dst = outp + (bh * T_ + t0 + row) * D_ + half;
    *(uint4*)(dst)      = d0;
    *(uint4*)(dst + 8)  = d1;
    *(uint4*)(dst + 16) = d2;
    *(uint4*)(dst + 24) = d3;
  }
}

// ---------------------------------------------------------------------------
// Kernel 2: MFMA flash attention — coalesced staging (round-10, validated).
// grid=(T/64, H, B), block=256 (4 waves = 4 Q-tiles of 16 rows).
// ---------------------------------------------------------------------------
__global__ __launch_bounds__(256) void attn_kernel(
    const unsigned short* __restrict__ q, const unsigned short* __restrict__ k,
    const unsigned short* __restrict__ vt, unsigned short* __restrict__ comb)
{
  __shared__ unsigned short Kt[64 * LD_];   // [key][d]
  __shared__ unsigned short Vt[64 * LD_];   // [d][key]
  __shared__ unsigned short Pl[4][16 * LD_];

  const int tid  = threadIdx.x;
  const int w    = tid >> 6;
  const int lane = tid & 63;
  const int m16  = lane & 15;
  const int quad = lane >> 4;
  const int h = blockIdx.y, b = blockIdx.z;
  const size_t bh = (size_t)(b * H_ + h);
  const int q0 = blockIdx.x * 64 + w * 16;

  U4 aQ0, aQ1;
  {
    const unsigned short* qrow = q + (bh * T_ + q0 + m16) * (size_t)D_;
    aQ0.u = *(const uint4*)(qrow + quad * 8);
    aQ1.u = *(const uint4*)(qrow + 32 + quad * 8);
  }

  f32x4 o0 = {0.f, 0.f, 0.f, 0.f}, o1 = o0, o2 = o0, o3 = o0;
  float mrow[4] = {-1e30f, -1e30f, -1e30f, -1e30f};
  float lrow[4] = {0.f, 0.f, 0.f, 0.f};

  const unsigned short* kb  = k  + bh * (size_t)(T_ * D_);
  const unsigned short* vtb = vt + bh * (size_t)(D_ * VTS_);
  unsigned short* Pw = &Pl[w][0];

  const int sr = tid >> 3;          // 0..31
  const int sc = (tid & 7) * 8;     // 0,8,...,56

  for (int kt = 0; kt < T_; kt += 64) {
    __syncthreads();
    {
      const uint4 ka = *(const uint4*)(kb + (size_t)(kt + sr) * D_ + sc);
      const uint4 kc = *(const uint4*)(kb + (size_t)(kt + 32 + sr) * D_ + sc);
      *(uint4*)(Kt + sr * LD_ + sc)        = ka;
      *(uint4*)(Kt + (32 + sr) * LD_ + sc) = kc;
      const uint4 va = *(const uint4*)(vtb + (size_t)sr * VTS_ + kt + sc);
      const uint4 vc = *(const uint4*)(vtb + (size_t)(32 + sr) * VTS_ + kt + sc);
      *(uint4*)(Vt + sr * LD_ + sc)        = va;
      *(uint4*)(Vt + (32 + sr) * LD_ + sc) = vc;
    }
    __syncthreads();

    f32x4 s[4];
#pragma unroll
    for (int ct = 0; ct < 4; ct++) {
      U4 kf0, kf1;
      kf0.u = *(const uint4*)(Kt + (ct * 16 + m16) * LD_ + quad * 8);
      kf1.u = *(const uint4*)(Kt + (ct * 16 + m16) * LD_ + 32 + quad * 8);
      f32x4 z = {0.f, 0.f, 0.f, 0.f};
      z = __builtin_amdgcn_mfma_f32_16x16x32_f16(aQ0.h, kf0.h, z, 0, 0, 0);
      z = __builtin_amdgcn_mfma_f32_16x16x32_f16(aQ1.h, kf1.h, z, 0, 0, 0);
      s[ct] = z;
    }

    float al[4];
#pragma unroll
    for (int r = 0; r < 4; r++) {
      const float s0 = s[0][r] * 0.125f;
      const float s1 = s[1][r] * 0.125f;
      const float s2 = s[2][r] * 0.125f;
      const float s3 = s[3][r] * 0.125f;
      const float mt = rowmax16(fmaxf(fmaxf(s0, s1), fmaxf(s2, s3)));
      const float mn = fmaxf(mrow[r], mt);
      const float a  = __expf(mrow[r] - mn);
      const float p0 = __expf(s0 - mn);
      const float p1 = __expf(s1 - mn);
      const float p2 = __expf(s2 - mn);
      const float p3 = __expf(s3 - mn);
      const float rs = rowsum16(p0 + p1 + p2 + p3);
      lrow[r] = lrow[r] * a + rs;
      mrow[r] = mn;
      al[r] = a;
      unsigned short* Pr = Pw + (quad * 4 + r) * LD_ + m16;
      Pr[0]  = f2h(p0);
      Pr[16] = f2h(p1);
      Pr[32] = f2h(p2);
      Pr[48] = f2h(p3);
    }

#pragma unroll
    for (int r = 0; r < 4; r++) {
      o0[r] *= al[r]; o1[r] *= al[r]; o2[r] *= al[r]; o3[r] *= al[r];
    }

    U4 aP0, aP1;
    aP0.u = *(const uint4*)(Pw + m16 * LD_ + quad * 8);
    aP1.u = *(const uint4*)(Pw + m16 * LD_ + 32 + quad * 8);

#pragma unroll
    for (int ct = 0; ct < 4; ct++) {
      U4 vf0, vf1;
      vf0.u = *(const uint4*)(Vt + (ct * 16 + m16) * LD_ + quad * 8);
      vf1.u = *(const uint4*)(Vt + (ct * 16 + m16) * LD_ + 32 + quad * 8);
      f32x4* op = (ct == 0) ? &o0 : (ct == 1) ? &o1 : (ct == 2) ? &o2 : &o3;
      *op = __builtin_amdgcn_mfma_f32_16x16x32_f16(aP0.h, vf0.h, *op, 0, 0, 0);
      *op = __builtin_amdgcn_mfma_f32_16x16x32_f16(aP1.h, vf1.h, *op, 0, 0, 0);
    }
  }

#pragma unroll
  for (int r = 0; r < 4; r++) {
    const float inv = 1.f / lrow[r];
    const int t = q0 + quad * 4 + r;
    unsigned short* dst = comb + ((size_t)b * T_ + t) * E_ + h * D_;
    dst[m16]      = f2h(o0[r] * inv);
    dst[16 + m16] = f2h(o1[r] * inv);
    dst[32 + m16] = f2h(o2[r] * inv);
    dst[48 + m16] = f2h(o3[r] * inv);
  }
}

// ---------------------------------------------------------------------------
// Kernel 3: out = comb @ Wo + x, coalesced LDS staging.
// grid=(B*T/128, E/64), block=256 (4 waves). Block: 128 n x 64 j.
// ---------------------------------------------------------------------------
__global__ __launch_bounds__(256) void out_mfma(
    const unsigned short* __restrict__ comb, const unsigned short* __restrict__ wot,
    const float* __restrict__ x, float* __restrict__ out)
{
  __shared__ unsigned short cs[128 * LD_];   // [n][e]
  __shared__ unsigned short wsb[64 * LD_];   // [j][e]

  const int tid = threadIdx.x;
  const int w = tid >> 6, lane = tid & 63;
  const int m16 = lane & 15, quad = lane >> 4;
  const int n0 = blockIdx.x * 128;
  const int j0 = blockIdx.y * 64;

  const int sr = tid >> 3;          // 0..31
  const int sc = (tid & 7) * 8;     // 0,8,...,56

  f32x4 acc[2][4];
#pragma unroll
  for (int rt = 0; rt < 2; rt++)
#pragma unroll
    for (int ct = 0; ct < 4; ct++) acc[rt][ct] = (f32x4){0.f, 0.f, 0.f, 0.f};

  for (int e0 = 0; e0 < E_; e0 += 64) {
    __syncthreads();
#pragma unroll
    for (int it = 0; it < 4; it++) {
      const int row = it * 32 + sr;
      *(uint4*)(cs + row * LD_ + sc) =
          *(const uint4*)(comb + (size_t)(n0 + row) * E_ + e0 + sc);
    }
#pragma unroll
    for (int it = 0; it < 2; it++) {
      const int row = it * 32 + sr;
      *(uint4*)(wsb + row * LD_ + sc) =
          *(const uint4*)(wot + (size_t)(j0 + row) * E_ + e0 + sc);
    }
    __syncthreads();

#pragma unroll
    for (int kk = 0; kk < 64; kk += 32) {
      U4 a0, a1, bf[4];
      a0.u = *(const uint4*)(cs + (w * 32 + m16) * LD_ + kk + quad * 8);
      a1.u = *(const uint4*)(cs + (w * 32 + 16 + m16) * LD_ + kk + quad * 8);
#pragma unroll
      for (int ct = 0; ct < 4; ct++)
        bf[ct].u = *(const uint4*)(wsb + (ct * 16 + m16) * LD_ + kk + quad * 8);
#pragma unroll
      for (int ct = 0; ct < 4; ct++) {
        acc[0][ct] = __builtin_amdgcn_mfma_f32_16x16x32_f16(a0.h, bf[ct].h, acc[0][ct], 0, 0, 0);
        acc[1][ct] = __builtin_amdgcn_mfma_f32_16x16x32_f16(a1.h, bf[ct].h, acc[1][ct], 0, 0, 0);
      }
    }
  }

  const int nw = n0 + w * 32;
#pragma unroll
  for (int rt = 0; rt < 2; rt++)
#pragma unroll
    for (int r = 0; r < 4; r++) {
      const int n = nw + rt * 16 + quad * 4 + r;
      const float* xr = x + (size_t)n * E_ + j0;
      float* orow = out + (size_t)n * E_ + j0;
#pragma unroll
      for (int ct = 0; ct < 4; ct++) {
        const int j = ct * 16 + m16;
        orow[j] = acc[rt][ct][r] + xr[j];
      }
    }
}

// ---------------------------------------------------------------------------
extern "C" void kernel_launch(void* const* d_in, const int* in_sizes, int n_in,
                              void* d_out, int out_size, void* d_ws, size_t ws_size,
                              hipStream_t stream) {
  (void)in_sizes; (void)n_in; (void)out_size; (void)ws_size;

  const float* x  = (const float*)d_in[0];
  const float* Wq = (const float*)d_in[1];
  const float* Wk = (const float*)d_in[2];
  const float* Wv = (const float*)d_in[3];
  const float* Wo = (const float*)d_in[4];
  float* out = (float*)d_out;

  unsigned short* ws0  = (unsigned short*)d_ws;
  unsigned short* xh   = ws0;                    // 4M elems (aliases comb)
  unsigned short* wt   = ws0 + 4194304;          // 3M
  unsigned short* wot  = ws0 + 7340032;          // 1M
  unsigned short* qh   = ws0 + 8388608;          // 4M
  unsigned short* kh   = ws0 + 12582912;         // 4M
  unsigned short* vth  = ws0 + 16777216;         // 32*64*2176 = 4.46M (padded)
  unsigned short* comb = xh;                     // alias: xh dead after qkv

  cvt_x<<<dim3(B_ * T_ * E_ / 1024), dim3(256), 0, stream>>>(x, xh);
  tconv_w<<<dim3(E_ / 64, H_, 3), dim3(256), 0, stream>>>(Wq, Wk, Wv, wt);
  tconv_wo<<<dim3(E_ / 64, E_ / 64), dim3(256), 0, stream>>>(Wo, wot);

  qkv_mfma<<<dim3(B_ * T_ / 128, H_, 3), dim3(256), 0, stream>>>(xh, wt, qh, kh, vth);

  attn_kernel<<<dim3(T_ / 64, H_, B_), dim3(256), 0, stream>>>(qh, kh, vth, comb);

  out_mfma<<<dim3(B_ * T_ / 128, E_ / 64), dim3(256), 0, stream>>>(comb, wot, x, out);
}